// Round 10
// baseline (754.187 us; speedup 1.0000x reference)
//
#include <hip/hip_runtime.h>
#include <hip/hip_bf16.h>
#include <math.h>

#define T_TOK 8192
#define DM    1024
#define DFF   4096
#define NE    8
#define DH    512
#define NSLOT (T_TOK*2)
#define MAXT  136   // 128-row tiles bound
#define MAXT2 72    // 256-row tiles bound

typedef float  f32x4  __attribute__((ext_vector_type(4)));
typedef __bf16 bf16x8 __attribute__((ext_vector_type(8)));

__device__ inline ushort f2bf(float f) {
  union { float f; unsigned int u; } v; v.f = f;
  unsigned int r = (v.u + 0x7FFFu + ((v.u >> 16) & 1u)) >> 16;
  return (ushort)r;
}

__device__ inline float bf2f(ushort u) {
  union { unsigned int i; float f; } v; v.i = ((unsigned int)u) << 16; return v.f;
}

// branch-free erf-based GELU (A&S 7.1.26, max abs err ~1.5e-7)
__device__ __forceinline__ float gelu_erf(float v) {
  float xx = v * 0.70710678118654752f;
  float ax = fabsf(xx);
  float t  = __builtin_amdgcn_rcpf(1.f + 0.3275911f * ax);
  float p  = t * (0.254829592f + t * (-0.284496736f + t * (1.421413741f +
             t * (-1.453152027f + t * 1.061405429f))));
  float er = 1.f - p * __expf(-ax * ax);
  er = copysignf(er, xx);
  return 0.5f * v * (1.f + er);
}

__device__ inline void gl_lds16(const void* g, void* l) {
  __builtin_amdgcn_global_load_lds(
      (const __attribute__((address_space(1))) unsigned int*)g,
      (__attribute__((address_space(3))) unsigned int*)l, 16, 0, 0);
}

#define SBAR  __builtin_amdgcn_s_barrier()

// ---------------- utility ----------------
// x -> bf16 hi (xh) + lo residual (xl); block 0 also inits routing scratch
__global__ void k_cvt_x(const float* __restrict__ x, ushort* __restrict__ xh,
                        ushort* __restrict__ xl, int n4,
                        int* counts, int* fill, float* psum) {
  if (blockIdx.x == 0 && threadIdx.x < NE) {
    counts[threadIdx.x] = 0; fill[threadIdx.x] = 0; psum[threadIdx.x] = 0.f;
  }
  int i = blockIdx.x * blockDim.x + threadIdx.x;
  int st = gridDim.x * blockDim.x;
  for (; i < n4; i += st) {
    float4 v = ((const float4*)x)[i];
    ushort4 h, l;
    h.x = f2bf(v.x); l.x = f2bf(v.x - bf2f(h.x));
    h.y = f2bf(v.y); l.y = f2bf(v.y - bf2f(h.y));
    h.z = f2bf(v.z); l.z = f2bf(v.z - bf2f(h.z));
    h.w = f2bf(v.w); l.w = f2bf(v.w - bf2f(h.w));
    ((ushort4*)xh)[i] = h;
    ((ushort4*)xl)[i] = l;
  }
}

// transpose f32 [R][C] -> bf16 [C][R], vectorized (float4 loads, ushort4 writes)
__global__ __launch_bounds__(256) void k_tr(const float* __restrict__ in,
                                            ushort* __restrict__ out, int R, int C) {
  __shared__ float tile[64][65];
  int e = blockIdx.z;
  in  += (size_t)e * R * C;
  out += (size_t)e * R * C;
  int r0 = blockIdx.y * 64, c0 = blockIdx.x * 64;
  int t = threadIdx.x;
  int lr = t >> 4, lc = (t & 15) * 4;
#pragma unroll
  for (int i = 0; i < 4; i++) {
    int r = lr + i * 16;
    float4 v = *(const float4*)&in[(size_t)(r0 + r) * C + c0 + lc];
    tile[r][lc] = v.x; tile[r][lc + 1] = v.y; tile[r][lc + 2] = v.z; tile[r][lc + 3] = v.w;
  }
  __syncthreads();
  int g = t & 15, cc = t >> 4;
#pragma unroll
  for (int i = 0; i < 4; i++) {
    int c = cc + i * 16;
    ushort4 o;
    o.x = f2bf(tile[g * 4 + 0][c]);
    o.y = f2bf(tile[g * 4 + 1][c]);
    o.z = f2bf(tile[g * 4 + 2][c]);
    o.w = f2bf(tile[g * 4 + 3][c]);
    *(ushort4*)&out[(size_t)(c0 + c) * R + r0 + g * 4] = o;
  }
}

// transpose gw1 f32 [1024][512] -> bf16 hi/lo [512][1024]
__global__ __launch_bounds__(256) void k_trg(const float* __restrict__ in,
                                             ushort* __restrict__ outh,
                                             ushort* __restrict__ outl) {
  __shared__ float tile[64][65];
  int r0 = blockIdx.y * 64, c0 = blockIdx.x * 64;
  int tx = threadIdx.x & 63, ty = threadIdx.x >> 6;
  for (int i = 0; i < 16; i++) {
    int r = ty + i * 4;
    tile[r][tx] = in[(size_t)(r0 + r) * DH + c0 + tx];
  }
  __syncthreads();
  for (int i = 0; i < 16; i++) {
    int c = ty + i * 4;
    float f = tile[tx][c];
    ushort h = f2bf(f);
    outh[(size_t)(c0 + c) * DM + r0 + tx] = h;
    outl[(size_t)(c0 + c) * DM + r0 + tx] = f2bf(f - bf2f(h));
  }
}

// ---------------- gating GEMM1 via split-bf16 MFMA ----------------
__global__ __launch_bounds__(256) void k_gate1m(const ushort* __restrict__ xh,
                                                const ushort* __restrict__ xl,
                                                const ushort* __restrict__ w1ht,
                                                const ushort* __restrict__ w1lt,
                                                const float* __restrict__ b,
                                                float* __restrict__ g1) {
  constexpr int GX = DH / 128;             // 4
  constexpr int NWG = GX * (T_TOK / 128);  // 256, %8==0
  int id = blockIdx.y * GX + blockIdx.x;
  int wg = (id & 7) * (NWG / 8) + (id >> 3);
  int m0 = (wg / GX) * 128;
  int n0 = (wg % GX) * 128;

  __shared__ ushort lds[2][16384];

  int t = threadIdx.x;
  int wave = t >> 6, lane = t & 63;
  int wr = wave >> 1, wc = wave & 1;

  int r = t >> 2;
  int csrc = (((t & 3) ^ ((t >> 3) & 3)) * 8);
  const ushort* ah0 = xh + (size_t)(m0 + r) * DM + csrc;
  const ushort* ah1 = xh + (size_t)(m0 + r + 64) * DM + csrc;
  const ushort* al0 = xl + (size_t)(m0 + r) * DM + csrc;
  const ushort* al1 = xl + (size_t)(m0 + r + 64) * DM + csrc;
  const ushort* bh0 = w1ht + (size_t)(n0 + r) * DM + csrc;
  const ushort* bh1 = w1ht + (size_t)(n0 + r + 64) * DM + csrc;
  const ushort* bl0 = w1lt + (size_t)(n0 + r) * DM + csrc;
  const ushort* bl1 = w1lt + (size_t)(n0 + r + 64) * DM + csrc;

  auto stage = [&](int b_, int k0) {
    ushort* base = lds[b_];
    gl_lds16(ah0 + k0, base + t * 8);
    gl_lds16(ah1 + k0, base + (t + 256) * 8);
    gl_lds16(al0 + k0, base + 4096 + t * 8);
    gl_lds16(al1 + k0, base + 4096 + (t + 256) * 8);
    gl_lds16(bh0 + k0, base + 8192 + t * 8);
    gl_lds16(bh1 + k0, base + 8192 + (t + 256) * 8);
    gl_lds16(bl0 + k0, base + 12288 + t * 8);
    gl_lds16(bl1 + k0, base + 12288 + (t + 256) * 8);
  };

  f32x4 acc[4][4] = {};
  int la = lane & 15;
  int kqs = (((lane >> 4) ^ ((la >> 1) & 3)) * 8);
  constexpr int NT = DM / 32;

  stage(0, 0);
  stage(1, 32);
  for (int kt = 0; kt < NT; kt++) {
    if (kt + 1 < NT) asm volatile("s_waitcnt vmcnt(8)" ::: "memory");
    else             asm volatile("s_waitcnt vmcnt(0)" ::: "memory");
    __builtin_amdgcn_s_barrier();
    const ushort* bb = lds[kt & 1];
    bf16x8 fah[4], fal[4], fbh[4], fbl[4];
#pragma unroll
    for (int m = 0; m < 4; m++) {
      int ro = (wr * 64 + m * 16 + la) * 32 + kqs;
      fah[m] = *(const bf16x8*)&bb[ro];
      fal[m] = *(const bf16x8*)&bb[4096 + ro];
    }
#pragma unroll
    for (int n = 0; n < 4; n++) {
      int ro = (wc * 64 + n * 16 + la) * 32 + kqs;
      fbh[n] = *(const bf16x8*)&bb[8192 + ro];
      fbl[n] = *(const bf16x8*)&bb[12288 + ro];
    }
    asm volatile("s_waitcnt lgkmcnt(0)" ::: "memory");
    __builtin_amdgcn_s_barrier();
    if (kt + 2 < NT) stage(kt & 1, (kt + 2) * 32);
#pragma unroll
    for (int m = 0; m < 4; m++)
#pragma unroll
      for (int n = 0; n < 4; n++)
        acc[m][n] = __builtin_amdgcn_mfma_f32_16x16x32_bf16(fah[m], fbh[n], acc[m][n], 0, 0, 0);
#pragma unroll
    for (int m = 0; m < 4; m++)
#pragma unroll
      for (int n = 0; n < 4; n++)
        acc[m][n] = __builtin_amdgcn_mfma_f32_16x16x32_bf16(fah[m], fbl[n], acc[m][n], 0, 0, 0);
#pragma unroll
    for (int m = 0; m < 4; m++)
#pragma unroll
      for (int n = 0; n < 4; n++)
        acc[m][n] = __builtin_amdgcn_mfma_f32_16x16x32_bf16(fal[m], fbh[n], acc[m][n], 0, 0, 0);
  }

#pragma unroll
  for (int m = 0; m < 4; m++) {
    int rbase = m0 + wr * 64 + m * 16 + ((lane >> 4) << 2);
#pragma unroll
    for (int n = 0; n < 4; n++) {
      int c = n0 + wc * 64 + n * 16 + la;
      float bv = b[c];
      f32x4 a = acc[m][n];
#pragma unroll
      for (int j = 0; j < 4; j++)
        g1[(size_t)(rbase + j) * DH + c] = fmaxf(a[j] + bv, 0.f);
    }
  }
}

// logits = g1 @ gw2 + gb2
__global__ __launch_bounds__(256) void k_gate2(const float* __restrict__ g1,
                                               const float* __restrict__ w2,
                                               const float* __restrict__ b2,
                                               float* __restrict__ logits) {
  int wave = threadIdx.x >> 6, lane = threadIdx.x & 63;
  int tok = blockIdx.x * 4 + wave;
  const float* row = &g1[(size_t)tok * DH];
  float v[8];
#pragma unroll
  for (int j = 0; j < 8; j++) v[j] = row[lane + 64 * j];
  float acc[8];
#pragma unroll
  for (int e = 0; e < NE; e++) {
    float s = 0.f;
#pragma unroll
    for (int j = 0; j < 8; j++) s += v[j] * w2[(size_t)(lane + 64 * j) * NE + e];
    acc[e] = s;
  }
  for (int off = 32; off > 0; off >>= 1)
#pragma unroll
    for (int e = 0; e < NE; e++) acc[e] += __shfl_down(acc[e], off);
  if (lane == 0)
#pragma unroll
    for (int e = 0; e < NE; e++) logits[(size_t)tok * NE + e] = acc[e] + b2[e];
}

// ---------------- routing ----------------
__global__ __launch_bounds__(256) void k_route(const float* __restrict__ logits,
                                               int* __restrict__ topi,
                                               float* __restrict__ gatesw,
                                               int* __restrict__ counts,
                                               float* __restrict__ psum) {
  int t = blockIdx.x * blockDim.x + threadIdx.x;
  const float* lp = &logits[(size_t)t * NE];
  float l[8];
#pragma unroll
  for (int e = 0; e < NE; e++) l[e] = lp[e];
  int i0 = 0; float v0 = l[0];
#pragma unroll
  for (int e = 1; e < NE; e++) if (l[e] > v0) { v0 = l[e]; i0 = e; }
  int i1 = (i0 == 0) ? 1 : 0; float v1 = l[i1];
#pragma unroll
  for (int e = 0; e < NE; e++)
    if (e != i0 && l[e] > v1) { v1 = l[e]; i1 = e; }
  float g0 = 1.f / (1.f + expf(v1 - v0));
  topi[t * 2] = i0; topi[t * 2 + 1] = i1;
  gatesw[t * 2] = g0; gatesw[t * 2 + 1] = 1.f - g0;
  float p[8]; float s = 0.f;
#pragma unroll
  for (int e = 0; e < NE; e++) { p[e] = expf(l[e] - v0); s += p[e]; }
  float inv = 1.f / s;
  int lane = threadIdx.x & 63;
#pragma unroll
  for (int e = 0; e < NE; e++) {
    float pe = p[e] * inv;
    for (int off = 32; off > 0; off >>= 1) pe += __shfl_down(pe, off);
    if (lane == 0) atomicAdd(&psum[e], pe);
  }
#pragma unroll
  for (int e = 0; e < NE; e++) {
    unsigned long long m0 = __ballot(i0 == e);
    unsigned long long m1 = __ballot(i1 == e);
    if (lane == 0) {
      int c = __popcll(m0) + __popcll(m1);
      if (c) atomicAdd(&counts[e], c);
    }
  }
}

// prefix-scan + loss + dense work-lists at 128- and 256-row granularity
__global__ void k_scan(const int* __restrict__ counts, int* __restrict__ offsets,
                       const float* __restrict__ psum, float* __restrict__ loss_out,
                       int* __restrict__ tile_e, int* __restrict__ tile_mt,
                       int* __restrict__ tile_e2, int* __restrict__ tile_mt2) {
  if (threadIdx.x == 0) {
    int off = 0;
    for (int e = 0; e < NE; e++) { offsets[e] = off; off += counts[e]; }
    offsets[NE] = off;
    float tt = 1.f / NE, loss = 0.f;
    for (int e = 0; e < NE; e++) {
      float pe = psum[e] / (float)T_TOK;
      loss += tt * (logf(tt) - logf(pe + 1e-8f));
    }
    loss_out[0] = loss;
    int n = 0;
    for (int e = 0; e < NE; e++) {
      int rows = counts[e];
      for (int mt = 0; mt * 128 < rows; mt++) { tile_e[n] = e; tile_mt[n] = mt; n++; }
    }
    for (int i = n; i < MAXT; i++) { tile_e[i] = -1; tile_mt[i] = 0; }
    n = 0;
    for (int e = 0; e < NE; e++) {
      int rows = counts[e];
      for (int mt = 0; mt * 256 < rows; mt++) { tile_e2[n] = e; tile_mt2[n] = mt; n++; }
    }
    for (int i = n; i < MAXT2; i++) { tile_e2[i] = -1; tile_mt2[i] = 0; }
  }
}

__global__ __launch_bounds__(256) void k_fill(const int* __restrict__ topi,
                                              const int* __restrict__ offsets,
                                              int* __restrict__ fill,
                                              int* __restrict__ slot_tok,
                                              int* __restrict__ tok_slot) {
  int t = blockIdx.x * blockDim.x + threadIdx.x;
  for (int k = 0; k < 2; k++) {
    int e = topi[t * 2 + k];
    int pos = offsets[e] + atomicAdd(&fill[e], 1);
    slot_tok[pos] = t;
    tok_slot[t * 2 + k] = pos;
  }
}

// ============ GEMM1: 256x256 tile, 8 waves, BK=32, single-barrier counted-vmcnt ============
// LDS: 3-buffer ring, A[256][32] + B[256][32] bf16 per buffer (32 KB) = 96 KB.
// Swizzle: phys chunk p = q ^ ((row>>1)&3); staged via pre-swizzled global col, read via kqs.
__global__ __launch_bounds__(512, 2) void k_egemm1(const ushort* __restrict__ xb,
                                                   const ushort* __restrict__ w1t,
                                                   const float* __restrict__ be1,
                                                   const int* __restrict__ slot_tok,
                                                   const int* __restrict__ offsets,
                                                   const int* __restrict__ tile_e2,
                                                   const int* __restrict__ tile_mt2,
                                                   ushort* __restrict__ H) {
  constexpr int GX = DFF / 256;    // 16
  constexpr int NWG = GX * MAXT2;  // 1152, %8==0
  constexpr int NT = DM / 32;      // 32
  int id = blockIdx.y * GX + blockIdx.x;
  int wg = (id & 7) * (NWG / 8) + (id >> 3);
  int ty = wg / GX;
  int n0c = (wg % GX) * 256;
  int e = tile_e2[ty];
  if (e < 0) return;
  int mt = tile_mt2[ty];
  int beg = offsets[e], nrows = offsets[e + 1] - beg;
  const ushort* Bw = w1t + (size_t)e * DFF * DM;

  __shared__ ushort As[3][8192];
  __shared__ ushort Bs[3][8192];

  int t = threadIdx.x;
  int lane = t & 63, la = lane & 15, lh = lane >> 4;
  int wid = t >> 6, wm = wid >> 2, wn = wid & 3;   // 2 x 4 wave grid

  int csrc = (((t & 3) ^ ((t >> 3) & 3)) * 8);
  auto arow = [&](int r) {
    r = mt * 256 + r; if (r >= nrows) r = nrows - 1;
    return (size_t)slot_tok[beg + r];
  };
  int rr0 = t >> 2;
  const ushort* aptr0 = xb + arow(rr0) * DM + csrc;
  const ushort* aptr1 = xb + arow(128 + rr0) * DM + csrc;
  const ushort* bptr0 = Bw + (size_t)(n0c + rr0) * DM + csrc;
  const ushort* bptr1 = Bw + (size_t)(n0c + 128 + rr0) * DM + csrc;
  char* adst = (char*)As + t * 16;
  char* bdst = (char*)Bs + t * 16;

  auto stage = [&](int b, int k0) {
    gl_lds16(aptr0 + k0, adst + b * 16384);
    gl_lds16(aptr1 + k0, adst + b * 16384 + 8192);
    gl_lds16(bptr0 + k0, bdst + b * 16384);
    gl_lds16(bptr1 + k0, bdst + b * 16384 + 8192);
  };

  f32x4 acc[8][4] = {};
  int kqs = (((lane >> 4) ^ ((la >> 1) & 3)) * 8);

  stage(0, 0);
  stage(1, 32);
  asm volatile("s_waitcnt vmcnt(4)" ::: "memory");
  SBAR;
  for (int kt = 0; kt < NT; kt++) {
    if (kt + 2 < NT) stage((kt + 2) % 3, (kt + 2) * 32);
    const ushort* Ab = As[kt % 3];
    const ushort* Bb = Bs[kt % 3];
    bf16x8 af[8], bfr[4];
#pragma unroll
    for (int m = 0; m < 8; m++)
      af[m] = *(const bf16x8*)&Ab[(wm * 128 + m * 16 + la) * 32 + kqs];
#pragma unroll
    for (int n = 0; n < 4; n++)
      bfr[n] = *(const bf16x8*)&Bb[(wn * 64 + n * 16 + la) * 32 + kqs];
    asm volatile("s_waitcnt lgkmcnt(0)" ::: "memory");
    __builtin_amdgcn_s_setprio(1);
#pragma unroll
    for (int m = 0; m < 8; m++)
#pragma unroll
      for (int n = 0; n < 4; n++)
        acc[m][n] = __builtin_amdgcn_mfma_f32_16x16x32_bf16(af[m], bfr[n], acc[m][n], 0, 0, 0);
    __builtin_amdgcn_s_setprio(0);
    if (kt + 2 < NT)      { asm volatile("s_waitcnt vmcnt(4)" ::: "memory"); SBAR; }
    else if (kt + 1 < NT) { asm volatile("s_waitcnt vmcnt(0)" ::: "memory"); SBAR; }
  }

#pragma unroll
  for (int m = 0; m < 8; m++) {
    int lrow = mt * 256 + wm * 128 + m * 16 + lh * 4;
#pragma unroll
    for (int n = 0; n < 4; n++) {
      int c = n0c + wn * 64 + n * 16 + la;
      float b1 = be1[e * DFF + c];
      f32x4 a = acc[m][n];
#pragma unroll
      for (int j = 0; j < 4; j++) {
        int rr = lrow + j;
        if (rr < nrows)
          H[(size_t)(beg + rr) * DFF + c] = f2bf(gelu_erf(a[j] + b1));
      }
    }
  }
}

// ============ GEMM2: 128x128 tile, 4 waves, BK=32, single-barrier counted-vmcnt ============
__global__ __launch_bounds__(256, 3) void k_egemm2(const ushort* __restrict__ H,
                                                   const ushort* __restrict__ w2t,
                                                   const float* __restrict__ be2,
                                                   const float* __restrict__ escale,
                                                   const float* __restrict__ ebias,
                                                   const int* __restrict__ offsets,
                                                   const int* __restrict__ tile_e,
                                                   const int* __restrict__ tile_mt,
                                                   ushort* __restrict__ eo) {
  constexpr int GX = DM / 128;            // 8
  constexpr int NWG = GX * MAXT;          // 1088, %8==0
  int id = blockIdx.y * GX + blockIdx.x;
  int wg = (id & 7) * (NWG / 8) + (id >> 3);
  int ty = wg / GX;
  int n0 = (wg % GX) * 128;
  int e = tile_e[ty];
  if (e < 0) return;
  int mt = tile_mt[ty];
  int beg = offsets[e], nrows = offsets[e + 1] - beg;
  const ushort* B = w2t + (size_t)e * DM * DFF;

  __shared__ ushort As[3][4096];
  __shared__ ushort Bs[3][4096];

  int t = threadIdx.x;
  int wave = t >> 6, lane = t & 63;
  int wr = wave >> 1, wc = wave & 1;

  int r_g0 = mt * 128 + (t >> 2);
  int r_g1 = r_g0 + 64;
  int s0 = beg + (r_g0 < nrows ? r_g0 : 0);
  int s1 = beg + (r_g1 < nrows ? r_g1 : 0);
  int acol = (((t & 3) ^ ((t >> 3) & 3)) * 8);
  const ushort* aptr0 = H + (size_t)s0 * DFF + acol;
  const ushort* aptr1 = H + (size_t)s1 * DFF + acol;
  const ushort* bptr0 = B + (size_t)(n0 + (t >> 2)) * DFF + acol;
  const ushort* bptr1 = B + (size_t)(n0 + (t >> 2) + 64) * DFF + acol;
  char* adst = (char*)As + t * 16;
  char* bdst = (char*)Bs + t * 16;

  auto stage = [&](int b, int k0) {
    gl_lds16(aptr0 + k0, adst + b * 8192);
    gl_lds16(aptr1 + k0, adst + b * 8192 + 4096);
    gl_lds16(bptr0 + k0, bdst + b * 8192);
    gl_lds16(bptr1 + k0, bdst + b * 8192 + 4096);
  };

  f32x4 acc[4][4] = {};
  int la = lane & 15;
  int kqs = (((lane >> 4) ^ ((la >> 1) & 3)) * 8);
  constexpr int NT = DFF / 32;   // 128

  stage(0, 0);
  stage(1, 32);
  asm volatile("s_waitcnt vmcnt(4)" ::: "memory");
  SBAR;
  for (int kt = 0; kt < NT; kt++) {
    if (kt + 2 < NT) stage((kt + 2) % 3, (kt + 2) * 32);
    const ushort* Ab = As[kt % 3];
    const ushort* Bb = Bs[kt % 3];
    bf16x8 af[4], bfr[4];
#pragma unroll
    for (int m = 0; m < 4; m++)
      af[m] = *(const bf16x8*)&Ab[(wr * 64 + m * 16 + la) * 32 + kqs];
#pragma unroll
    for (int n = 0; n < 4; n++)
      bfr[n] = *(const bf16x8*)&Bb[(wc * 64 + n * 16 + la) * 32 + kqs];
    asm volatile("s_waitcnt lgkmcnt(0)" ::: "memory");
    __builtin_amdgcn_s_setprio(1);
#pragma unroll
    for (int m = 0; m < 4; m++)
#pragma unroll
      for (int n = 0; n < 4; n++)
        acc[m][n] = __builtin_amdgcn_mfma_f32_16x16x32_bf16(af[m], bfr[n], acc[m][n], 0, 0, 0);
    __builtin_amdgcn_s_setprio(0);
    if (kt + 2 < NT)      { asm volatile("s_waitcnt vmcnt(4)" ::: "memory"); SBAR; }
    else if (kt + 1 < NT) { asm volatile("s_waitcnt vmcnt(0)" ::: "memory"); SBAR; }
  }

  int row0 = mt * 128 + wr * 64;
  int c_of = n0 + wc * 64;
#pragma unroll
  for (int m = 0; m < 4; m++) {
    int rbase = row0 + m * 16 + ((lane >> 4) << 2);
#pragma unroll
    for (int n = 0; n < 4; n++) {
      int c = c_of + n * 16 + la;
      float b2 = be2[e * DM + c];
      float sc = escale[e * DM + c];
      float bb = ebias[e * DM + c];
      f32x4 a = acc[m][n];
#pragma unroll
      for (int j = 0; j < 4; j++) {
        int rr = rbase + j;
        if (rr < nrows) {
          float v = (a[j] + b2) * sc + bb;
          eo[(size_t)(beg + rr) * DM + c] = f2bf(v);
        }
      }
    }
  }
}

// ---------------- gather + residual + LayerNorm ----------------
__global__ __launch_bounds__(256) void k_ln(const float* __restrict__ x,
                                            const ushort* __restrict__ eo,
                                            const int* __restrict__ tok_slot,
                                            const float* __restrict__ gatesw,
                                            const float* __restrict__ gamma,
                                            const float* __restrict__ beta,
                                            float* __restrict__ y) {
  int t = blockIdx.x;
  int s0 = tok_slot[t * 2], s1 = tok_slot[t * 2 + 1];
  float g0 = gatesw[t * 2], g1 = gatesw[t * 2 + 1];
  const float* xr = &x[(size_t)t * DM];
  const ushort* e0 = &eo[(size_t)s0 * DM];
  const ushort* e1 = &eo[(size_t)s1 * DM];
  int tid = threadIdx.x;
  int c0 = tid * 4;
  float4 xv = *(const float4*)&xr[c0];
  ushort4 a0 = *(const ushort4*)&e0[c0];
  ushort4 a1 = *(const ushort4*)&e1[c0];
  float v[4];
  v[0] = xv.x + g0 * bf2f(a0.x) + g1 * bf2f(a1.x);
  v[1] = xv.y + g0 * bf2f(a0.y) + g1 * bf2f(a1.y);
  v[2] = xv.z + g0 * bf2f(a0.z) + g1 * bf2f(a1.z);
  v[3] = xv.w + g0 * bf2f(a0.w) + g1 * bf2f(a1.w);
  float sum = v[0] + v[1] + v[2] + v[3];
  __shared__ float red[4];
  __shared__ float red2[4];
  for (int off = 32; off > 0; off >>= 1) sum += __shfl_down(sum, off);
  if ((tid & 63) == 0) red[tid >> 6] = sum;
  __syncthreads();
  float mu = (red[0] + red[1] + red[2] + red[3]) * (1.f / DM);
  float vs = 0.f;
#pragma unroll
  for (int i = 0; i < 4; i++) { float d = v[i] - mu; vs += d * d; }
  for (int off = 32; off > 0; off >>= 1) vs += __shfl_down(vs, off);
  if ((tid & 63) == 0) red2[tid >> 6] = vs;
  __syncthreads();
  float var = (red2[0] + red2[1] + red2[2] + red2[3]) * (1.f / DM);
  float rs = rsqrtf(var + 1e-5f);
  float4 gm = *(const float4*)&gamma[c0];
  float4 bt = *(const float4*)&beta[c0];
  float4 o;
  o.x = (v[0] - mu) * rs * gm.x + bt.x;
  o.y = (v[1] - mu) * rs * gm.y + bt.y;
  o.z = (v[2] - mu) * rs * gm.z + bt.z;
  o.w = (v[3] - mu) * rs * gm.w + bt.w;
  *(float4*)&y[(size_t)t * DM + c0] = o;
}

extern "C" void kernel_launch(void* const* d_in, const int* in_sizes, int n_in,
                              void* d_out, int out_size, void* d_ws, size_t ws_size,
                              hipStream_t stream) {
  const float* x    = (const float*)d_in[0];
  const float* gw1  = (const float*)d_in[1];
  const float* gb1  = (const float*)d_in[2];
  const float* gw2  = (const float*)d_in[3];
  const float* gb2  = (const float*)d_in[4];
  const float* we1  = (const float*)d_in[5];
  const float* be1  = (const float*)d_in[6];
  const float* we2  = (const float*)d_in[7];
  const float* be2  = (const float*)d_in[8];
  const float* escale = (const float*)d_in[9];
  const float* ebias  = (const float*)d_in[10];
  const float* gamma  = (const float*)d_in[11];
  const float* beta   = (const float*)d_in[12];
  float* y = (float*)d_out;
  float* loss_out = y + (size_t)T_TOK * DM;

  char* w = (char*)d_ws;
  ushort* xh    = (ushort*)w; w += (size_t)T_TOK * DM * 2;
  ushort* xl    = (ushort*)w; w += (size_t)T_TOK * DM * 2;
  ushort* w1t   = (ushort*)w; w += (size_t)NE * DFF * DM * 2;
  ushort* w2t   = (ushort*)w; w += (size_t)NE * DM * DFF * 2;
  ushort* H     = (ushort*)w; w += (size_t)NSLOT * DFF * 2;
  ushort* eo    = (ushort*)w; w += (size_t)NSLOT * DM * 2;
  ushort* w1ht  = (ushort*)w; w += (size_t)DH * DM * 2;
  ushort* w1lt  = (ushort*)w; w += (size_t)DH * DM * 2;
  float* g1     = (float*)w;  w += (size_t)T_TOK * DH * 4;
  float* logits = (float*)w;  w += (size_t)T_TOK * NE * 4;
  int*   topi   = (int*)w;    w += (size_t)T_TOK * 2 * 4;
  float* gatesw = (float*)w;  w += (size_t)T_TOK * 2 * 4;
  int* slot_tok = (int*)w;    w += (size_t)NSLOT * 4;
  int* tok_slot = (int*)w;    w += (size_t)T_TOK * 2 * 4;
  int* counts   = (int*)w;    w += 64;
  int* fill     = (int*)w;    w += 64;
  int* offsets  = (int*)w;    w += 64;
  float* psum   = (float*)w;  w += 64;
  int* tile_e   = (int*)w;    w += MAXT * 4 + 32;
  int* tile_mt  = (int*)w;    w += MAXT * 4 + 32;
  int* tile_e2  = (int*)w;    w += MAXT2 * 4 + 32;
  int* tile_mt2 = (int*)w;    w += MAXT2 * 4 + 32;

  k_cvt_x<<<2048, 256, 0, stream>>>(x, xh, xl, T_TOK * DM / 4, counts, fill, psum);
  k_trg<<<dim3(8, 16), 256, 0, stream>>>(gw1, w1ht, w1lt);
  k_tr<<<dim3(64, 16, 8), 256, 0, stream>>>(we1, w1t, DM, DFF);
  k_tr<<<dim3(16, 64, 8), 256, 0, stream>>>(we2, w2t, DFF, DM);
  k_gate1m<<<dim3(DH / 128, T_TOK / 128), 256, 0, stream>>>(xh, xl, w1ht, w1lt, gb1, g1);
  k_gate2<<<T_TOK / 4, 256, 0, stream>>>(g1, gw2, gb2, logits);
  k_route<<<T_TOK / 256, 256, 0, stream>>>(logits, topi, gatesw, counts, psum);
  k_scan<<<1, 64, 0, stream>>>(counts, offsets, psum, loss_out, tile_e, tile_mt,
                               tile_e2, tile_mt2);
  k_fill<<<T_TOK / 256, 256, 0, stream>>>(topi, offsets, fill, slot_tok, tok_slot);
  k_egemm1<<<dim3(DFF / 256, MAXT2), 512, 0, stream>>>(xh, w1t, be1, slot_tok, offsets,
                                                       tile_e2, tile_mt2, H);
  k_egemm2<<<dim3(DM / 128, MAXT), 256, 0, stream>>>(H, w2t, be2, escale, ebias,
                                                     offsets, tile_e, tile_mt, eo);
  k_ln<<<T_TOK, 256, 0, stream>>>(x, eo, tok_slot, gatesw, gamma, beta, y);
}

// Round 11
// 682.085 us; speedup vs baseline: 1.1057x; 1.1057x over previous
//
#include <hip/hip_runtime.h>
#include <hip/hip_bf16.h>
#include <math.h>

#define T_TOK 8192
#define DM    1024
#define DFF   4096
#define NE    8
#define DH    512
#define NSLOT (T_TOK*2)
#define MAXT  136   // max 128-row tiles across experts: 16384/128 + 8

typedef float  f32x4  __attribute__((ext_vector_type(4)));
typedef __bf16 bf16x8 __attribute__((ext_vector_type(8)));

__device__ inline ushort f2bf(float f) {
  union { float f; unsigned int u; } v; v.f = f;
  unsigned int r = (v.u + 0x7FFFu + ((v.u >> 16) & 1u)) >> 16;
  return (ushort)r;
}

__device__ inline float bf2f(ushort u) {
  union { unsigned int i; float f; } v; v.i = ((unsigned int)u) << 16; return v.f;
}

// branch-free erf-based GELU (A&S 7.1.26, max abs err ~1.5e-7)
__device__ __forceinline__ float gelu_erf(float v) {
  float xx = v * 0.70710678118654752f;
  float ax = fabsf(xx);
  float t  = __builtin_amdgcn_rcpf(1.f + 0.3275911f * ax);
  float p  = t * (0.254829592f + t * (-0.284496736f + t * (1.421413741f +
             t * (-1.453152027f + t * 1.061405429f))));
  float er = 1.f - p * __expf(-ax * ax);
  er = copysignf(er, xx);
  return 0.5f * v * (1.f + er);
}

__device__ inline void gl_lds16(const void* g, void* l) {
  __builtin_amdgcn_global_load_lds(
      (const __attribute__((address_space(1))) unsigned int*)g,
      (__attribute__((address_space(3))) unsigned int*)l, 16, 0, 0);
}

// ---------------- utility ----------------
// x -> bf16 hi (xh) + lo residual (xl); block 0 also inits routing scratch
__global__ void k_cvt_x(const float* __restrict__ x, ushort* __restrict__ xh,
                        ushort* __restrict__ xl, int n4,
                        int* counts, int* fill, float* psum) {
  if (blockIdx.x == 0 && threadIdx.x < NE) {
    counts[threadIdx.x] = 0; fill[threadIdx.x] = 0; psum[threadIdx.x] = 0.f;
  }
  int i = blockIdx.x * blockDim.x + threadIdx.x;
  int st = gridDim.x * blockDim.x;
  for (; i < n4; i += st) {
    float4 v = ((const float4*)x)[i];
    ushort4 h, l;
    h.x = f2bf(v.x); l.x = f2bf(v.x - bf2f(h.x));
    h.y = f2bf(v.y); l.y = f2bf(v.y - bf2f(h.y));
    h.z = f2bf(v.z); l.z = f2bf(v.z - bf2f(h.z));
    h.w = f2bf(v.w); l.w = f2bf(v.w - bf2f(h.w));
    ((ushort4*)xh)[i] = h;
    ((ushort4*)xl)[i] = l;
  }
}

// transpose f32 [R][C] -> bf16 [C][R], vectorized (float4 loads, ushort4 writes)
__global__ __launch_bounds__(256) void k_tr(const float* __restrict__ in,
                                            ushort* __restrict__ out, int R, int C) {
  __shared__ float tile[64][65];
  int e = blockIdx.z;
  in  += (size_t)e * R * C;
  out += (size_t)e * R * C;
  int r0 = blockIdx.y * 64, c0 = blockIdx.x * 64;
  int t = threadIdx.x;
  int lr = t >> 4, lc = (t & 15) * 4;
#pragma unroll
  for (int i = 0; i < 4; i++) {
    int r = lr + i * 16;
    float4 v = *(const float4*)&in[(size_t)(r0 + r) * C + c0 + lc];
    tile[r][lc] = v.x; tile[r][lc + 1] = v.y; tile[r][lc + 2] = v.z; tile[r][lc + 3] = v.w;
  }
  __syncthreads();
  int g = t & 15, cc = t >> 4;
#pragma unroll
  for (int i = 0; i < 4; i++) {
    int c = cc + i * 16;
    ushort4 o;
    o.x = f2bf(tile[g * 4 + 0][c]);
    o.y = f2bf(tile[g * 4 + 1][c]);
    o.z = f2bf(tile[g * 4 + 2][c]);
    o.w = f2bf(tile[g * 4 + 3][c]);
    *(ushort4*)&out[(size_t)(c0 + c) * R + r0 + g * 4] = o;
  }
}

// transpose gw1 f32 [1024][512] -> bf16 hi/lo [512][1024]
__global__ __launch_bounds__(256) void k_trg(const float* __restrict__ in,
                                             ushort* __restrict__ outh,
                                             ushort* __restrict__ outl) {
  __shared__ float tile[64][65];
  int r0 = blockIdx.y * 64, c0 = blockIdx.x * 64;
  int tx = threadIdx.x & 63, ty = threadIdx.x >> 6;
  for (int i = 0; i < 16; i++) {
    int r = ty + i * 4;
    tile[r][tx] = in[(size_t)(r0 + r) * DH + c0 + tx];
  }
  __syncthreads();
  for (int i = 0; i < 16; i++) {
    int c = ty + i * 4;
    float f = tile[tx][c];
    ushort h = f2bf(f);
    outh[(size_t)(c0 + c) * DM + r0 + tx] = h;
    outl[(size_t)(c0 + c) * DM + r0 + tx] = f2bf(f - bf2f(h));
  }
}

// ---------------- gating GEMM1 via split-bf16 MFMA ----------------
__global__ __launch_bounds__(256) void k_gate1m(const ushort* __restrict__ xh,
                                                const ushort* __restrict__ xl,
                                                const ushort* __restrict__ w1ht,
                                                const ushort* __restrict__ w1lt,
                                                const float* __restrict__ b,
                                                float* __restrict__ g1) {
  constexpr int GX = DH / 128;             // 4
  constexpr int NWG = GX * (T_TOK / 128);  // 256, %8==0
  int id = blockIdx.y * GX + blockIdx.x;
  int wg = (id & 7) * (NWG / 8) + (id >> 3);
  int m0 = (wg / GX) * 128;
  int n0 = (wg % GX) * 128;

  __shared__ ushort lds[2][16384];

  int t = threadIdx.x;
  int wave = t >> 6, lane = t & 63;
  int wr = wave >> 1, wc = wave & 1;

  int r = t >> 2;
  int csrc = (((t & 3) ^ ((t >> 3) & 3)) * 8);
  const ushort* ah0 = xh + (size_t)(m0 + r) * DM + csrc;
  const ushort* ah1 = xh + (size_t)(m0 + r + 64) * DM + csrc;
  const ushort* al0 = xl + (size_t)(m0 + r) * DM + csrc;
  const ushort* al1 = xl + (size_t)(m0 + r + 64) * DM + csrc;
  const ushort* bh0 = w1ht + (size_t)(n0 + r) * DM + csrc;
  const ushort* bh1 = w1ht + (size_t)(n0 + r + 64) * DM + csrc;
  const ushort* bl0 = w1lt + (size_t)(n0 + r) * DM + csrc;
  const ushort* bl1 = w1lt + (size_t)(n0 + r + 64) * DM + csrc;

  auto stage = [&](int b_, int k0) {
    ushort* base = lds[b_];
    gl_lds16(ah0 + k0, base + t * 8);
    gl_lds16(ah1 + k0, base + (t + 256) * 8);
    gl_lds16(al0 + k0, base + 4096 + t * 8);
    gl_lds16(al1 + k0, base + 4096 + (t + 256) * 8);
    gl_lds16(bh0 + k0, base + 8192 + t * 8);
    gl_lds16(bh1 + k0, base + 8192 + (t + 256) * 8);
    gl_lds16(bl0 + k0, base + 12288 + t * 8);
    gl_lds16(bl1 + k0, base + 12288 + (t + 256) * 8);
  };

  f32x4 acc[4][4] = {};
  int la = lane & 15;
  int kqs = (((lane >> 4) ^ ((la >> 1) & 3)) * 8);
  constexpr int NT = DM / 32;

  stage(0, 0);
  stage(1, 32);
  for (int kt = 0; kt < NT; kt++) {
    if (kt + 1 < NT) asm volatile("s_waitcnt vmcnt(8)" ::: "memory");
    else             asm volatile("s_waitcnt vmcnt(0)" ::: "memory");
    __builtin_amdgcn_s_barrier();
    const ushort* bb = lds[kt & 1];
    bf16x8 fah[4], fal[4], fbh[4], fbl[4];
#pragma unroll
    for (int m = 0; m < 4; m++) {
      int ro = (wr * 64 + m * 16 + la) * 32 + kqs;
      fah[m] = *(const bf16x8*)&bb[ro];
      fal[m] = *(const bf16x8*)&bb[4096 + ro];
    }
#pragma unroll
    for (int n = 0; n < 4; n++) {
      int ro = (wc * 64 + n * 16 + la) * 32 + kqs;
      fbh[n] = *(const bf16x8*)&bb[8192 + ro];
      fbl[n] = *(const bf16x8*)&bb[12288 + ro];
    }
    asm volatile("s_waitcnt lgkmcnt(0)" ::: "memory");
    __builtin_amdgcn_s_barrier();
    if (kt + 2 < NT) stage(kt & 1, (kt + 2) * 32);
#pragma unroll
    for (int m = 0; m < 4; m++)
#pragma unroll
      for (int n = 0; n < 4; n++)
        acc[m][n] = __builtin_amdgcn_mfma_f32_16x16x32_bf16(fah[m], fbh[n], acc[m][n], 0, 0, 0);
#pragma unroll
    for (int m = 0; m < 4; m++)
#pragma unroll
      for (int n = 0; n < 4; n++)
        acc[m][n] = __builtin_amdgcn_mfma_f32_16x16x32_bf16(fah[m], fbl[n], acc[m][n], 0, 0, 0);
#pragma unroll
    for (int m = 0; m < 4; m++)
#pragma unroll
      for (int n = 0; n < 4; n++)
        acc[m][n] = __builtin_amdgcn_mfma_f32_16x16x32_bf16(fal[m], fbh[n], acc[m][n], 0, 0, 0);
  }

#pragma unroll
  for (int m = 0; m < 4; m++) {
    int rbase = m0 + wr * 64 + m * 16 + ((lane >> 4) << 2);
#pragma unroll
    for (int n = 0; n < 4; n++) {
      int c = n0 + wc * 64 + n * 16 + la;
      float bv = b[c];
      f32x4 a = acc[m][n];
#pragma unroll
      for (int j = 0; j < 4; j++)
        g1[(size_t)(rbase + j) * DH + c] = fmaxf(a[j] + bv, 0.f);
    }
  }
}

// logits = g1 @ gw2 + gb2   [8192 x 8], K=512; one wave per token
__global__ __launch_bounds__(256) void k_gate2(const float* __restrict__ g1,
                                               const float* __restrict__ w2,
                                               const float* __restrict__ b2,
                                               float* __restrict__ logits) {
  int wave = threadIdx.x >> 6, lane = threadIdx.x & 63;
  int tok = blockIdx.x * 4 + wave;
  const float* row = &g1[(size_t)tok * DH];
  float v[8];
#pragma unroll
  for (int j = 0; j < 8; j++) v[j] = row[lane + 64 * j];
  float acc[8];
#pragma unroll
  for (int e = 0; e < NE; e++) {
    float s = 0.f;
#pragma unroll
    for (int j = 0; j < 8; j++) s += v[j] * w2[(size_t)(lane + 64 * j) * NE + e];
    acc[e] = s;
  }
  for (int off = 32; off > 0; off >>= 1)
#pragma unroll
    for (int e = 0; e < NE; e++) acc[e] += __shfl_down(acc[e], off);
  if (lane == 0)
#pragma unroll
    for (int e = 0; e < NE; e++) logits[(size_t)tok * NE + e] = acc[e] + b2[e];
}

// ---------------- routing ----------------
__global__ __launch_bounds__(256) void k_route(const float* __restrict__ logits,
                                               int* __restrict__ topi,
                                               float* __restrict__ gatesw,
                                               int* __restrict__ counts,
                                               float* __restrict__ psum) {
  int t = blockIdx.x * blockDim.x + threadIdx.x;
  const float* lp = &logits[(size_t)t * NE];
  float l[8];
#pragma unroll
  for (int e = 0; e < NE; e++) l[e] = lp[e];
  int i0 = 0; float v0 = l[0];
#pragma unroll
  for (int e = 1; e < NE; e++) if (l[e] > v0) { v0 = l[e]; i0 = e; }
  int i1 = (i0 == 0) ? 1 : 0; float v1 = l[i1];
#pragma unroll
  for (int e = 0; e < NE; e++)
    if (e != i0 && l[e] > v1) { v1 = l[e]; i1 = e; }
  float g0 = 1.f / (1.f + expf(v1 - v0));
  topi[t * 2] = i0; topi[t * 2 + 1] = i1;
  gatesw[t * 2] = g0; gatesw[t * 2 + 1] = 1.f - g0;
  float p[8]; float s = 0.f;
#pragma unroll
  for (int e = 0; e < NE; e++) { p[e] = expf(l[e] - v0); s += p[e]; }
  float inv = 1.f / s;
  int lane = threadIdx.x & 63;
#pragma unroll
  for (int e = 0; e < NE; e++) {
    float pe = p[e] * inv;
    for (int off = 32; off > 0; off >>= 1) pe += __shfl_down(pe, off);
    if (lane == 0) atomicAdd(&psum[e], pe);
  }
#pragma unroll
  for (int e = 0; e < NE; e++) {
    unsigned long long m0 = __ballot(i0 == e);
    unsigned long long m1 = __ballot(i1 == e);
    if (lane == 0) {
      int c = __popcll(m0) + __popcll(m1);
      if (c) atomicAdd(&counts[e], c);
    }
  }
}

// prefix-scan + load-balance loss + dense tile work-list
__global__ void k_scan(const int* __restrict__ counts, int* __restrict__ offsets,
                       const float* __restrict__ psum, float* __restrict__ loss_out,
                       int* __restrict__ tile_e, int* __restrict__ tile_mt) {
  if (threadIdx.x == 0) {
    int off = 0;
    for (int e = 0; e < NE; e++) { offsets[e] = off; off += counts[e]; }
    offsets[NE] = off;
    float tt = 1.f / NE, loss = 0.f;
    for (int e = 0; e < NE; e++) {
      float pe = psum[e] / (float)T_TOK;
      loss += tt * (logf(tt) - logf(pe + 1e-8f));
    }
    loss_out[0] = loss;
    int n = 0;
    for (int e = 0; e < NE; e++) {
      int rows = counts[e];
      for (int mt = 0; mt * 128 < rows; mt++) { tile_e[n] = e; tile_mt[n] = mt; n++; }
    }
    for (int i = n; i < MAXT; i++) { tile_e[i] = -1; tile_mt[i] = 0; }
  }
}

__global__ __launch_bounds__(256) void k_fill(const int* __restrict__ topi,
                                              const int* __restrict__ offsets,
                                              int* __restrict__ fill,
                                              int* __restrict__ slot_tok,
                                              int* __restrict__ tok_slot) {
  int t = blockIdx.x * blockDim.x + threadIdx.x;
  for (int k = 0; k < 2; k++) {
    int e = topi[t * 2 + k];
    int pos = offsets[e] + atomicAdd(&fill[e], 1);
    slot_tok[pos] = t;
    tok_slot[t * 2 + k] = pos;
  }
}

// ---------------- expert GEMMs: 128x128 tile, BK=32, 2-deep counted-vmcnt pipeline ----------------
// LDS swizzle: physical chunk p = logical chunk q ^ ((row>>1)&3)  (16B chunks, 4/row)
// GEMM1: H[slot, :] = gelu( xh[token] @ we1[e] + be1[e] ),  K=1024
__global__ __launch_bounds__(256, 3) void k_egemm1(const ushort* __restrict__ xb,
                                                   const ushort* __restrict__ w1t,
                                                   const float* __restrict__ be1,
                                                   const int* __restrict__ slot_tok,
                                                   const int* __restrict__ offsets,
                                                   const int* __restrict__ tile_e,
                                                   const int* __restrict__ tile_mt,
                                                   ushort* __restrict__ H) {
  constexpr int GX = DFF / 128;           // 32
  constexpr int NWG = GX * MAXT;          // 4352, %8==0
  int id = blockIdx.y * GX + blockIdx.x;
  int wg = (id & 7) * (NWG / 8) + (id >> 3);
  int ty = wg / GX;
  int n0 = (wg % GX) * 128;
  int e = tile_e[ty];
  if (e < 0) return;
  int mt = tile_mt[ty];
  int beg = offsets[e], nrows = offsets[e + 1] - beg;
  const ushort* B = w1t + (size_t)e * DFF * DM;

  __shared__ ushort As[2][4096];
  __shared__ ushort Bs[2][4096];

  int t = threadIdx.x;
  int wave = t >> 6, lane = t & 63;
  int wr = wave >> 1, wc = wave & 1;

  int r_g0 = mt * 128 + (t >> 2);
  int r_g1 = r_g0 + 64;
  int tok0 = slot_tok[beg + (r_g0 < nrows ? r_g0 : 0)];
  int tok1 = slot_tok[beg + (r_g1 < nrows ? r_g1 : 0)];
  int acol = (((t & 3) ^ ((t >> 3) & 3)) * 8);
  const ushort* aptr0 = xb + (size_t)tok0 * DM + acol;
  const ushort* aptr1 = xb + (size_t)tok1 * DM + acol;
  const ushort* bptr0 = B + (size_t)(n0 + (t >> 2)) * DM + acol;
  const ushort* bptr1 = B + (size_t)(n0 + (t >> 2) + 64) * DM + acol;
  char* adst = (char*)As + t * 16;
  char* bdst = (char*)Bs + t * 16;

  auto stage = [&](int b, int k0) {
    gl_lds16(aptr0 + k0, adst + b * 8192);
    gl_lds16(aptr1 + k0, adst + b * 8192 + 4096);
    gl_lds16(bptr0 + k0, bdst + b * 8192);
    gl_lds16(bptr1 + k0, bdst + b * 8192 + 4096);
  };

  f32x4 acc[4][4] = {};
  int la = lane & 15;
  int kqs = (((lane >> 4) ^ ((la >> 1) & 3)) * 8);
  constexpr int NT = DM / 32;

  stage(0, 0);
  stage(1, 32);
  for (int kt = 0; kt < NT; kt++) {
    if (kt + 1 < NT) asm volatile("s_waitcnt vmcnt(4)" ::: "memory");
    else             asm volatile("s_waitcnt vmcnt(0)" ::: "memory");
    __builtin_amdgcn_s_barrier();
    const ushort* Ab = As[kt & 1];
    const ushort* Bb = Bs[kt & 1];
    bf16x8 af[4], bfr[4];
#pragma unroll
    for (int m = 0; m < 4; m++)
      af[m] = *(const bf16x8*)&Ab[(wr * 64 + m * 16 + la) * 32 + kqs];
#pragma unroll
    for (int n = 0; n < 4; n++)
      bfr[n] = *(const bf16x8*)&Bb[(wc * 64 + n * 16 + la) * 32 + kqs];
    asm volatile("s_waitcnt lgkmcnt(0)" ::: "memory");
    __builtin_amdgcn_s_barrier();
    if (kt + 2 < NT) stage(kt & 1, (kt + 2) * 32);
#pragma unroll
    for (int m = 0; m < 4; m++)
#pragma unroll
      for (int n = 0; n < 4; n++)
        acc[m][n] = __builtin_amdgcn_mfma_f32_16x16x32_bf16(af[m], bfr[n], acc[m][n], 0, 0, 0);
  }

  int row0 = mt * 128 + wr * 64;
  int c_of = n0 + wc * 64;
#pragma unroll
  for (int m = 0; m < 4; m++) {
    int rbase = row0 + m * 16 + ((lane >> 4) << 2);
#pragma unroll
    for (int n = 0; n < 4; n++) {
      int c = c_of + n * 16 + la;
      float b1 = be1[e * DFF + c];
      f32x4 a = acc[m][n];
#pragma unroll
      for (int j = 0; j < 4; j++) {
        int rr = rbase + j;
        if (rr < nrows) {
          float v = a[j] + b1;
          H[(size_t)(beg + rr) * DFF + c] = f2bf(gelu_erf(v));
        }
      }
    }
  }
}

// GEMM2: eo[slot, :] = (H[slot] @ we2[e] + be2)*escale + ebias   (bf16, plain stores)
__global__ __launch_bounds__(256, 3) void k_egemm2(const ushort* __restrict__ H,
                                                   const ushort* __restrict__ w2t,
                                                   const float* __restrict__ be2,
                                                   const float* __restrict__ escale,
                                                   const float* __restrict__ ebias,
                                                   const int* __restrict__ offsets,
                                                   const int* __restrict__ tile_e,
                                                   const int* __restrict__ tile_mt,
                                                   ushort* __restrict__ eo) {
  constexpr int GX = DM / 128;            // 8
  constexpr int NWG = GX * MAXT;          // 1088, %8==0
  int id = blockIdx.y * GX + blockIdx.x;
  int wg = (id & 7) * (NWG / 8) + (id >> 3);
  int ty = wg / GX;
  int n0 = (wg % GX) * 128;
  int e = tile_e[ty];
  if (e < 0) return;
  int mt = tile_mt[ty];
  int beg = offsets[e], nrows = offsets[e + 1] - beg;
  const ushort* B = w2t + (size_t)e * DM * DFF;

  __shared__ ushort As[2][4096];
  __shared__ ushort Bs[2][4096];

  int t = threadIdx.x;
  int wave = t >> 6, lane = t & 63;
  int wr = wave >> 1, wc = wave & 1;

  int r_g0 = mt * 128 + (t >> 2);
  int r_g1 = r_g0 + 64;
  int s0 = beg + (r_g0 < nrows ? r_g0 : 0);
  int s1 = beg + (r_g1 < nrows ? r_g1 : 0);
  int acol = (((t & 3) ^ ((t >> 3) & 3)) * 8);
  const ushort* aptr0 = H + (size_t)s0 * DFF + acol;
  const ushort* aptr1 = H + (size_t)s1 * DFF + acol;
  const ushort* bptr0 = B + (size_t)(n0 + (t >> 2)) * DFF + acol;
  const ushort* bptr1 = B + (size_t)(n0 + (t >> 2) + 64) * DFF + acol;
  char* adst = (char*)As + t * 16;
  char* bdst = (char*)Bs + t * 16;

  auto stage = [&](int b, int k0) {
    gl_lds16(aptr0 + k0, adst + b * 8192);
    gl_lds16(aptr1 + k0, adst + b * 8192 + 4096);
    gl_lds16(bptr0 + k0, bdst + b * 8192);
    gl_lds16(bptr1 + k0, bdst + b * 8192 + 4096);
  };

  f32x4 acc[4][4] = {};
  int la = lane & 15;
  int kqs = (((lane >> 4) ^ ((la >> 1) & 3)) * 8);
  constexpr int NT = DFF / 32;

  stage(0, 0);
  stage(1, 32);
  for (int kt = 0; kt < NT; kt++) {
    if (kt + 1 < NT) asm volatile("s_waitcnt vmcnt(4)" ::: "memory");
    else             asm volatile("s_waitcnt vmcnt(0)" ::: "memory");
    __builtin_amdgcn_s_barrier();
    const ushort* Ab = As[kt & 1];
    const ushort* Bb = Bs[kt & 1];
    bf16x8 af[4], bfr[4];
#pragma unroll
    for (int m = 0; m < 4; m++)
      af[m] = *(const bf16x8*)&Ab[(wr * 64 + m * 16 + la) * 32 + kqs];
#pragma unroll
    for (int n = 0; n < 4; n++)
      bfr[n] = *(const bf16x8*)&Bb[(wc * 64 + n * 16 + la) * 32 + kqs];
    asm volatile("s_waitcnt lgkmcnt(0)" ::: "memory");
    __builtin_amdgcn_s_barrier();
    if (kt + 2 < NT) stage(kt & 1, (kt + 2) * 32);
#pragma unroll
    for (int m = 0; m < 4; m++)
#pragma unroll
      for (int n = 0; n < 4; n++)
        acc[m][n] = __builtin_amdgcn_mfma_f32_16x16x32_bf16(af[m], bfr[n], acc[m][n], 0, 0, 0);
  }

  int row0 = mt * 128 + wr * 64;
  int c_of = n0 + wc * 64;
#pragma unroll
  for (int m = 0; m < 4; m++) {
    int rbase = row0 + m * 16 + ((lane >> 4) << 2);
#pragma unroll
    for (int n = 0; n < 4; n++) {
      int c = c_of + n * 16 + la;
      float b2 = be2[e * DM + c];
      float sc = escale[e * DM + c];
      float bb = ebias[e * DM + c];
      f32x4 a = acc[m][n];
#pragma unroll
      for (int j = 0; j < 4; j++) {
        int rr = rbase + j;
        if (rr < nrows) {
          float v = (a[j] + b2) * sc + bb;
          eo[(size_t)(beg + rr) * DM + c] = f2bf(v);
        }
      }
    }
  }
}

// ---------------- gather + residual + LayerNorm ----------------
__global__ __launch_bounds__(256) void k_ln(const float* __restrict__ x,
                                            const ushort* __restrict__ eo,
                                            const int* __restrict__ tok_slot,
                                            const float* __restrict__ gatesw,
                                            const float* __restrict__ gamma,
                                            const float* __restrict__ beta,
                                            float* __restrict__ y) {
  int t = blockIdx.x;
  int s0 = tok_slot[t * 2], s1 = tok_slot[t * 2 + 1];
  float g0 = gatesw[t * 2], g1 = gatesw[t * 2 + 1];
  const float* xr = &x[(size_t)t * DM];
  const ushort* e0 = &eo[(size_t)s0 * DM];
  const ushort* e1 = &eo[(size_t)s1 * DM];
  int tid = threadIdx.x;
  int c0 = tid * 4;
  float4 xv = *(const float4*)&xr[c0];
  ushort4 a0 = *(const ushort4*)&e0[c0];
  ushort4 a1 = *(const ushort4*)&e1[c0];
  float v[4];
  v[0] = xv.x + g0 * bf2f(a0.x) + g1 * bf2f(a1.x);
  v[1] = xv.y + g0 * bf2f(a0.y) + g1 * bf2f(a1.y);
  v[2] = xv.z + g0 * bf2f(a0.z) + g1 * bf2f(a1.z);
  v[3] = xv.w + g0 * bf2f(a0.w) + g1 * bf2f(a1.w);
  float sum = v[0] + v[1] + v[2] + v[3];
  __shared__ float red[4];
  __shared__ float red2[4];
  for (int off = 32; off > 0; off >>= 1) sum += __shfl_down(sum, off);
  if ((tid & 63) == 0) red[tid >> 6] = sum;
  __syncthreads();
  float mu = (red[0] + red[1] + red[2] + red[3]) * (1.f / DM);
  float vs = 0.f;
#pragma unroll
  for (int i = 0; i < 4; i++) { float d = v[i] - mu; vs += d * d; }
  for (int off = 32; off > 0; off >>= 1) vs += __shfl_down(vs, off);
  if ((tid & 63) == 0) red2[tid >> 6] = vs;
  __syncthreads();
  float var = (red2[0] + red2[1] + red2[2] + red2[3]) * (1.f / DM);
  float rs = rsqrtf(var + 1e-5f);
  float4 gm = *(const float4*)&gamma[c0];
  float4 bt = *(const float4*)&beta[c0];
  float4 o;
  o.x = (v[0] - mu) * rs * gm.x + bt.x;
  o.y = (v[1] - mu) * rs * gm.y + bt.y;
  o.z = (v[2] - mu) * rs * gm.z + bt.z;
  o.w = (v[3] - mu) * rs * gm.w + bt.w;
  *(float4*)&y[(size_t)t * DM + c0] = o;
}

extern "C" void kernel_launch(void* const* d_in, const int* in_sizes, int n_in,
                              void* d_out, int out_size, void* d_ws, size_t ws_size,
                              hipStream_t stream) {
  const float* x    = (const float*)d_in[0];
  const float* gw1  = (const float*)d_in[1];
  const float* gb1  = (const float*)d_in[2];
  const float* gw2  = (const float*)d_in[3];
  const float* gb2  = (const float*)d_in[4];
  const float* we1  = (const float*)d_in[5];
  const float* be1  = (const float*)d_in[6];
  const float* we2  = (const float*)d_in[7];
  const float* be2  = (const float*)d_in[8];
  const float* escale = (const float*)d_in[9];
  const float* ebias  = (const float*)d_in[10];
  const float* gamma  = (const float*)d_in[11];
  const float* beta   = (const float*)d_in[12];
  float* y = (float*)d_out;
  float* loss_out = y + (size_t)T_TOK * DM;

  char* w = (char*)d_ws;
  ushort* xh    = (ushort*)w; w += (size_t)T_TOK * DM * 2;
  ushort* xl    = (ushort*)w; w += (size_t)T_TOK * DM * 2;
  ushort* w1t   = (ushort*)w; w += (size_t)NE * DFF * DM * 2;
  ushort* w2t   = (ushort*)w; w += (size_t)NE * DM * DFF * 2;
  ushort* H     = (ushort*)w; w += (size_t)NSLOT * DFF * 2;
  ushort* eo    = (ushort*)w; w += (size_t)NSLOT * DM * 2;
  ushort* w1ht  = (ushort*)w; w += (size_t)DH * DM * 2;
  ushort* w1lt  = (ushort*)w; w += (size_t)DH * DM * 2;
  float* g1     = (float*)w;  w += (size_t)T_TOK * DH * 4;
  float* logits = (float*)w;  w += (size_t)T_TOK * NE * 4;
  int*   topi   = (int*)w;    w += (size_t)T_TOK * 2 * 4;
  float* gatesw = (float*)w;  w += (size_t)T_TOK * 2 * 4;
  int* slot_tok = (int*)w;    w += (size_t)NSLOT * 4;
  int* tok_slot = (int*)w;    w += (size_t)T_TOK * 2 * 4;
  int* counts   = (int*)w;    w += 64;
  int* fill     = (int*)w;    w += 64;
  int* offsets  = (int*)w;    w += 64;
  float* psum   = (float*)w;  w += 64;
  int* tile_e   = (int*)w;    w += MAXT * 4 + 32;
  int* tile_mt  = (int*)w;    w += MAXT * 4 + 32;

  k_cvt_x<<<2048, 256, 0, stream>>>(x, xh, xl, T_TOK * DM / 4, counts, fill, psum);
  k_trg<<<dim3(8, 16), 256, 0, stream>>>(gw1, w1ht, w1lt);
  k_tr<<<dim3(64, 16, 8), 256, 0, stream>>>(we1, w1t, DM, DFF);
  k_tr<<<dim3(16, 64, 8), 256, 0, stream>>>(we2, w2t, DFF, DM);
  k_gate1m<<<dim3(DH / 128, T_TOK / 128), 256, 0, stream>>>(xh, xl, w1ht, w1lt, gb1, g1);
  k_gate2<<<T_TOK / 4, 256, 0, stream>>>(g1, gw2, gb2, logits);
  k_route<<<T_TOK / 256, 256, 0, stream>>>(logits, topi, gatesw, counts, psum);
  k_scan<<<1, 64, 0, stream>>>(counts, offsets, psum, loss_out, tile_e, tile_mt);
  k_fill<<<T_TOK / 256, 256, 0, stream>>>(topi, offsets, fill, slot_tok, tok_slot);
  k_egemm1<<<dim3(DFF / 128, MAXT), 256, 0, stream>>>(xh, w1t, be1, slot_tok, offsets,
                                                      tile_e, tile_mt, H);
  k_egemm2<<<dim3(DM / 128, MAXT), 256, 0, stream>>>(H, w2t, be2, escale, ebias,
                                                     offsets, tile_e, tile_mt, eo);
  k_ln<<<T_TOK, 256, 0, stream>>>(x, eo, tok_slot, gatesw, gamma, beta, y);
}

// Round 12
// 673.350 us; speedup vs baseline: 1.1201x; 1.0130x over previous
//
#include <hip/hip_runtime.h>
#include <hip/hip_bf16.h>
#include <math.h>

#define T_TOK 8192
#define DM    1024
#define DFF   4096
#define NE    8
#define DH    512
#define NSLOT (T_TOK*2)
#define MAXT  136   // max 128-row tiles across experts: 16384/128 + 8

typedef float  f32x4  __attribute__((ext_vector_type(4)));
typedef __bf16 bf16x8 __attribute__((ext_vector_type(8)));

__device__ inline ushort f2bf(float f) {
  union { float f; unsigned int u; } v; v.f = f;
  unsigned int r = (v.u + 0x7FFFu + ((v.u >> 16) & 1u)) >> 16;
  return (ushort)r;
}

__device__ inline float bf2f(ushort u) {
  union { unsigned int i; float f; } v; v.i = ((unsigned int)u) << 16; return v.f;
}

// branch-free erf-based GELU (A&S 7.1.26, max abs err ~1.5e-7)
__device__ __forceinline__ float gelu_erf(float v) {
  float xx = v * 0.70710678118654752f;
  float ax = fabsf(xx);
  float t  = __builtin_amdgcn_rcpf(1.f + 0.3275911f * ax);
  float p  = t * (0.254829592f + t * (-0.284496736f + t * (1.421413741f +
             t * (-1.453152027f + t * 1.061405429f))));
  float er = 1.f - p * __expf(-ax * ax);
  er = copysignf(er, xx);
  return 0.5f * v * (1.f + er);
}

__device__ inline void gl_lds16(const void* g, void* l) {
  __builtin_amdgcn_global_load_lds(
      (const __attribute__((address_space(1))) unsigned int*)g,
      (__attribute__((address_space(3))) unsigned int*)l, 16, 0, 0);
}

// ---------------- utility ----------------
// x -> bf16 hi (xh) + lo residual (xl); block 0 also inits routing scratch
__global__ void k_cvt_x(const float* __restrict__ x, ushort* __restrict__ xh,
                        ushort* __restrict__ xl, int n4,
                        int* counts, int* fill, float* psum) {
  if (blockIdx.x == 0 && threadIdx.x < NE) {
    counts[threadIdx.x] = 0; fill[threadIdx.x] = 0; psum[threadIdx.x] = 0.f;
  }
  int i = blockIdx.x * blockDim.x + threadIdx.x;
  int st = gridDim.x * blockDim.x;
  for (; i < n4; i += st) {
    float4 v = ((const float4*)x)[i];
    ushort4 h, l;
    h.x = f2bf(v.x); l.x = f2bf(v.x - bf2f(h.x));
    h.y = f2bf(v.y); l.y = f2bf(v.y - bf2f(h.y));
    h.z = f2bf(v.z); l.z = f2bf(v.z - bf2f(h.z));
    h.w = f2bf(v.w); l.w = f2bf(v.w - bf2f(h.w));
    ((ushort4*)xh)[i] = h;
    ((ushort4*)xl)[i] = l;
  }
}

// ---- all weight transposes in ONE launch ----
// x < 1024        : we1[e] f32 [1024][4096] -> w1t[e]  bf16 [4096][1024]
// 1024 <= x <2048 : we2[e] f32 [4096][1024] -> w2t[e]  bf16 [1024][4096]
// x >= 2048       : gw1    f32 [1024][512]  -> w1ht/w1lt bf16 [512][1024] (hi/lo split)
__global__ __launch_bounds__(256) void k_trall(const float* __restrict__ we1,
                                               const float* __restrict__ we2,
                                               const float* __restrict__ gw1,
                                               ushort* __restrict__ w1t,
                                               ushort* __restrict__ w2t,
                                               ushort* __restrict__ w1ht,
                                               ushort* __restrict__ w1lt) {
  __shared__ float tile[64][65];
  int x = blockIdx.x, e = blockIdx.y;
  int t = threadIdx.x;
  const float* in;
  int C, r0, c0, mode;
  if (x < 1024) {
    in = we1 + (size_t)e * DM * DFF;
    C = DFF; c0 = (x & 63) * 64; r0 = (x >> 6) * 64; mode = 0;
  } else if (x < 2048) {
    int x2 = x - 1024;
    in = we2 + (size_t)e * DFF * DM;
    C = DM; c0 = (x2 & 15) * 64; r0 = (x2 >> 4) * 64; mode = 1;
  } else {
    int tid = (x - 2048) + 16 * e;   // 0..127, unique per (x,e)
    in = gw1;
    C = DH; c0 = (tid & 7) * 64; r0 = (tid >> 3) * 64; mode = 2;
  }
  int lr = t >> 4, lc = (t & 15) * 4;
#pragma unroll
  for (int i = 0; i < 4; i++) {
    int r = lr + i * 16;
    float4 v = *(const float4*)&in[(size_t)(r0 + r) * C + c0 + lc];
    tile[r][lc] = v.x; tile[r][lc + 1] = v.y; tile[r][lc + 2] = v.z; tile[r][lc + 3] = v.w;
  }
  __syncthreads();
  int g = t & 15, cc = t >> 4;
  if (mode == 0) {
    ushort* out = w1t + (size_t)e * DM * DFF;
#pragma unroll
    for (int i = 0; i < 4; i++) {
      int c = cc + i * 16;
      ushort4 o;
      o.x = f2bf(tile[g * 4 + 0][c]);
      o.y = f2bf(tile[g * 4 + 1][c]);
      o.z = f2bf(tile[g * 4 + 2][c]);
      o.w = f2bf(tile[g * 4 + 3][c]);
      *(ushort4*)&out[(size_t)(c0 + c) * DM + r0 + g * 4] = o;
    }
  } else if (mode == 1) {
    ushort* out = w2t + (size_t)e * DFF * DM;
#pragma unroll
    for (int i = 0; i < 4; i++) {
      int c = cc + i * 16;
      ushort4 o;
      o.x = f2bf(tile[g * 4 + 0][c]);
      o.y = f2bf(tile[g * 4 + 1][c]);
      o.z = f2bf(tile[g * 4 + 2][c]);
      o.w = f2bf(tile[g * 4 + 3][c]);
      *(ushort4*)&out[(size_t)(c0 + c) * DFF + r0 + g * 4] = o;
    }
  } else {
#pragma unroll
    for (int i = 0; i < 4; i++) {
      int c = cc + i * 16;
      ushort4 oh, ol;
      float f0 = tile[g * 4 + 0][c], f1 = tile[g * 4 + 1][c];
      float f2 = tile[g * 4 + 2][c], f3 = tile[g * 4 + 3][c];
      oh.x = f2bf(f0); ol.x = f2bf(f0 - bf2f(oh.x));
      oh.y = f2bf(f1); ol.y = f2bf(f1 - bf2f(oh.y));
      oh.z = f2bf(f2); ol.z = f2bf(f2 - bf2f(oh.z));
      oh.w = f2bf(f3); ol.w = f2bf(f3 - bf2f(oh.w));
      *(ushort4*)&w1ht[(size_t)(c0 + c) * DM + r0 + g * 4] = oh;
      *(ushort4*)&w1lt[(size_t)(c0 + c) * DM + r0 + g * 4] = ol;
    }
  }
}

// ---------------- gating GEMM1 via split-bf16 MFMA ----------------
__global__ __launch_bounds__(256) void k_gate1m(const ushort* __restrict__ xh,
                                                const ushort* __restrict__ xl,
                                                const ushort* __restrict__ w1ht,
                                                const ushort* __restrict__ w1lt,
                                                const float* __restrict__ b,
                                                float* __restrict__ g1) {
  constexpr int GX = DH / 128;             // 4
  constexpr int NWG = GX * (T_TOK / 128);  // 256, %8==0
  int id = blockIdx.y * GX + blockIdx.x;
  int wg = (id & 7) * (NWG / 8) + (id >> 3);
  int m0 = (wg / GX) * 128;
  int n0 = (wg % GX) * 128;

  __shared__ ushort lds[2][16384];

  int t = threadIdx.x;
  int wave = t >> 6, lane = t & 63;
  int wr = wave >> 1, wc = wave & 1;

  int r = t >> 2;
  int csrc = (((t & 3) ^ ((t >> 3) & 3)) * 8);
  const ushort* ah0 = xh + (size_t)(m0 + r) * DM + csrc;
  const ushort* ah1 = xh + (size_t)(m0 + r + 64) * DM + csrc;
  const ushort* al0 = xl + (size_t)(m0 + r) * DM + csrc;
  const ushort* al1 = xl + (size_t)(m0 + r + 64) * DM + csrc;
  const ushort* bh0 = w1ht + (size_t)(n0 + r) * DM + csrc;
  const ushort* bh1 = w1ht + (size_t)(n0 + r + 64) * DM + csrc;
  const ushort* bl0 = w1lt + (size_t)(n0 + r) * DM + csrc;
  const ushort* bl1 = w1lt + (size_t)(n0 + r + 64) * DM + csrc;

  auto stage = [&](int b_, int k0) {
    ushort* base = lds[b_];
    gl_lds16(ah0 + k0, base + t * 8);
    gl_lds16(ah1 + k0, base + (t + 256) * 8);
    gl_lds16(al0 + k0, base + 4096 + t * 8);
    gl_lds16(al1 + k0, base + 4096 + (t + 256) * 8);
    gl_lds16(bh0 + k0, base + 8192 + t * 8);
    gl_lds16(bh1 + k0, base + 8192 + (t + 256) * 8);
    gl_lds16(bl0 + k0, base + 12288 + t * 8);
    gl_lds16(bl1 + k0, base + 12288 + (t + 256) * 8);
  };

  f32x4 acc[4][4] = {};
  int la = lane & 15;
  int kqs = (((lane >> 4) ^ ((la >> 1) & 3)) * 8);
  constexpr int NT = DM / 32;

  stage(0, 0);
  stage(1, 32);
  for (int kt = 0; kt < NT; kt++) {
    if (kt + 1 < NT) asm volatile("s_waitcnt vmcnt(8)" ::: "memory");
    else             asm volatile("s_waitcnt vmcnt(0)" ::: "memory");
    __builtin_amdgcn_s_barrier();
    const ushort* bb = lds[kt & 1];
    bf16x8 fah[4], fal[4], fbh[4], fbl[4];
#pragma unroll
    for (int m = 0; m < 4; m++) {
      int ro = (wr * 64 + m * 16 + la) * 32 + kqs;
      fah[m] = *(const bf16x8*)&bb[ro];
      fal[m] = *(const bf16x8*)&bb[4096 + ro];
    }
#pragma unroll
    for (int n = 0; n < 4; n++) {
      int ro = (wc * 64 + n * 16 + la) * 32 + kqs;
      fbh[n] = *(const bf16x8*)&bb[8192 + ro];
      fbl[n] = *(const bf16x8*)&bb[12288 + ro];
    }
    asm volatile("s_waitcnt lgkmcnt(0)" ::: "memory");
    __builtin_amdgcn_s_barrier();
    if (kt + 2 < NT) stage(kt & 1, (kt + 2) * 32);
#pragma unroll
    for (int m = 0; m < 4; m++)
#pragma unroll
      for (int n = 0; n < 4; n++)
        acc[m][n] = __builtin_amdgcn_mfma_f32_16x16x32_bf16(fah[m], fbh[n], acc[m][n], 0, 0, 0);
#pragma unroll
    for (int m = 0; m < 4; m++)
#pragma unroll
      for (int n = 0; n < 4; n++)
        acc[m][n] = __builtin_amdgcn_mfma_f32_16x16x32_bf16(fah[m], fbl[n], acc[m][n], 0, 0, 0);
#pragma unroll
    for (int m = 0; m < 4; m++)
#pragma unroll
      for (int n = 0; n < 4; n++)
        acc[m][n] = __builtin_amdgcn_mfma_f32_16x16x32_bf16(fal[m], fbh[n], acc[m][n], 0, 0, 0);
  }

#pragma unroll
  for (int m = 0; m < 4; m++) {
    int rbase = m0 + wr * 64 + m * 16 + ((lane >> 4) << 2);
#pragma unroll
    for (int n = 0; n < 4; n++) {
      int c = n0 + wc * 64 + n * 16 + la;
      float bv = b[c];
      f32x4 a = acc[m][n];
#pragma unroll
      for (int j = 0; j < 4; j++)
        g1[(size_t)(rbase + j) * DH + c] = fmaxf(a[j] + bv, 0.f);
    }
  }
}

// logits = g1 @ gw2 + gb2   [8192 x 8], K=512; one wave per token
__global__ __launch_bounds__(256) void k_gate2(const float* __restrict__ g1,
                                               const float* __restrict__ w2,
                                               const float* __restrict__ b2,
                                               float* __restrict__ logits) {
  int wave = threadIdx.x >> 6, lane = threadIdx.x & 63;
  int tok = blockIdx.x * 4 + wave;
  const float* row = &g1[(size_t)tok * DH];
  float v[8];
#pragma unroll
  for (int j = 0; j < 8; j++) v[j] = row[lane + 64 * j];
  float acc[8];
#pragma unroll
  for (int e = 0; e < NE; e++) {
    float s = 0.f;
#pragma unroll
    for (int j = 0; j < 8; j++) s += v[j] * w2[(size_t)(lane + 64 * j) * NE + e];
    acc[e] = s;
  }
  for (int off = 32; off > 0; off >>= 1)
#pragma unroll
    for (int e = 0; e < NE; e++) acc[e] += __shfl_down(acc[e], off);
  if (lane == 0)
#pragma unroll
    for (int e = 0; e < NE; e++) logits[(size_t)tok * NE + e] = acc[e] + b2[e];
}

// ---------------- routing ----------------
__global__ __launch_bounds__(256) void k_route(const float* __restrict__ logits,
                                               int* __restrict__ topi,
                                               float* __restrict__ gatesw,
                                               int* __restrict__ counts,
                                               float* __restrict__ psum) {
  int t = blockIdx.x * blockDim.x + threadIdx.x;
  const float* lp = &logits[(size_t)t * NE];
  float l[8];
#pragma unroll
  for (int e = 0; e < NE; e++) l[e] = lp[e];
  int i0 = 0; float v0 = l[0];
#pragma unroll
  for (int e = 1; e < NE; e++) if (l[e] > v0) { v0 = l[e]; i0 = e; }
  int i1 = (i0 == 0) ? 1 : 0; float v1 = l[i1];
#pragma unroll
  for (int e = 0; e < NE; e++)
    if (e != i0 && l[e] > v1) { v1 = l[e]; i1 = e; }
  float g0 = 1.f / (1.f + expf(v1 - v0));
  topi[t * 2] = i0; topi[t * 2 + 1] = i1;
  gatesw[t * 2] = g0; gatesw[t * 2 + 1] = 1.f - g0;
  float p[8]; float s = 0.f;
#pragma unroll
  for (int e = 0; e < NE; e++) { p[e] = expf(l[e] - v0); s += p[e]; }
  float inv = 1.f / s;
  int lane = threadIdx.x & 63;
#pragma unroll
  for (int e = 0; e < NE; e++) {
    float pe = p[e] * inv;
    for (int off = 32; off > 0; off >>= 1) pe += __shfl_down(pe, off);
    if (lane == 0) atomicAdd(&psum[e], pe);
  }
#pragma unroll
  for (int e = 0; e < NE; e++) {
    unsigned long long m0 = __ballot(i0 == e);
    unsigned long long m1 = __ballot(i1 == e);
    if (lane == 0) {
      int c = __popcll(m0) + __popcll(m1);
      if (c) atomicAdd(&counts[e], c);
    }
  }
}

// prefix-scan + load-balance loss + dense tile work-list
__global__ void k_scan(const int* __restrict__ counts, int* __restrict__ offsets,
                       const float* __restrict__ psum, float* __restrict__ loss_out,
                       int* __restrict__ tile_e, int* __restrict__ tile_mt) {
  if (threadIdx.x == 0) {
    int off = 0;
    for (int e = 0; e < NE; e++) { offsets[e] = off; off += counts[e]; }
    offsets[NE] = off;
    float tt = 1.f / NE, loss = 0.f;
    for (int e = 0; e < NE; e++) {
      float pe = psum[e] / (float)T_TOK;
      loss += tt * (logf(tt) - logf(pe + 1e-8f));
    }
    loss_out[0] = loss;
    int n = 0;
    for (int e = 0; e < NE; e++) {
      int rows = counts[e];
      for (int mt = 0; mt * 128 < rows; mt++) { tile_e[n] = e; tile_mt[n] = mt; n++; }
    }
    for (int i = n; i < MAXT; i++) { tile_e[i] = -1; tile_mt[i] = 0; }
  }
}

__global__ __launch_bounds__(256) void k_fill(const int* __restrict__ topi,
                                              const int* __restrict__ offsets,
                                              int* __restrict__ fill,
                                              int* __restrict__ slot_tok,
                                              int* __restrict__ tok_slot) {
  int t = blockIdx.x * blockDim.x + threadIdx.x;
  for (int k = 0; k < 2; k++) {
    int e = topi[t * 2 + k];
    int pos = offsets[e] + atomicAdd(&fill[e], 1);
    slot_tok[pos] = t;
    tok_slot[t * 2 + k] = pos;
  }
}

// ---------------- expert GEMMs: 128x128 tile, BK=32, 2-deep counted-vmcnt pipeline ----------------
// LDS swizzle: physical chunk p = logical chunk q ^ ((row>>1)&3)  (16B chunks, 4/row)
// GEMM1: H[slot, :] = gelu( xh[token] @ we1[e] + be1[e] ),  K=1024
__global__ __launch_bounds__(256, 3) void k_egemm1(const ushort* __restrict__ xb,
                                                   const ushort* __restrict__ w1t,
                                                   const float* __restrict__ be1,
                                                   const int* __restrict__ slot_tok,
                                                   const int* __restrict__ offsets,
                                                   const int* __restrict__ tile_e,
                                                   const int* __restrict__ tile_mt,
                                                   ushort* __restrict__ H) {
  constexpr int GX = DFF / 128;           // 32
  constexpr int NWG = GX * MAXT;          // 4352, %8==0
  int id = blockIdx.y * GX + blockIdx.x;
  int wg = (id & 7) * (NWG / 8) + (id >> 3);
  int ty = wg / GX;
  int n0 = (wg % GX) * 128;
  int e = tile_e[ty];
  if (e < 0) return;
  int mt = tile_mt[ty];
  int beg = offsets[e], nrows = offsets[e + 1] - beg;
  const ushort* B = w1t + (size_t)e * DFF * DM;

  __shared__ ushort As[2][4096];
  __shared__ ushort Bs[2][4096];

  int t = threadIdx.x;
  int wave = t >> 6, lane = t & 63;
  int wr = wave >> 1, wc = wave & 1;

  int r_g0 = mt * 128 + (t >> 2);
  int r_g1 = r_g0 + 64;
  int tok0 = slot_tok[beg + (r_g0 < nrows ? r_g0 : 0)];
  int tok1 = slot_tok[beg + (r_g1 < nrows ? r_g1 : 0)];
  int acol = (((t & 3) ^ ((t >> 3) & 3)) * 8);
  const ushort* aptr0 = xb + (size_t)tok0 * DM + acol;
  const ushort* aptr1 = xb + (size_t)tok1 * DM + acol;
  const ushort* bptr0 = B + (size_t)(n0 + (t >> 2)) * DM + acol;
  const ushort* bptr1 = B + (size_t)(n0 + (t >> 2) + 64) * DM + acol;
  char* adst = (char*)As + t * 16;
  char* bdst = (char*)Bs + t * 16;

  auto stage = [&](int b, int k0) {
    gl_lds16(aptr0 + k0, adst + b * 8192);
    gl_lds16(aptr1 + k0, adst + b * 8192 + 4096);
    gl_lds16(bptr0 + k0, bdst + b * 8192);
    gl_lds16(bptr1 + k0, bdst + b * 8192 + 4096);
  };

  f32x4 acc[4][4] = {};
  int la = lane & 15;
  int kqs = (((lane >> 4) ^ ((la >> 1) & 3)) * 8);
  constexpr int NT = DM / 32;

  stage(0, 0);
  stage(1, 32);
  for (int kt = 0; kt < NT; kt++) {
    if (kt + 1 < NT) asm volatile("s_waitcnt vmcnt(4)" ::: "memory");
    else             asm volatile("s_waitcnt vmcnt(0)" ::: "memory");
    __builtin_amdgcn_s_barrier();
    const ushort* Ab = As[kt & 1];
    const ushort* Bb = Bs[kt & 1];
    bf16x8 af[4], bfr[4];
#pragma unroll
    for (int m = 0; m < 4; m++)
      af[m] = *(const bf16x8*)&Ab[(wr * 64 + m * 16 + la) * 32 + kqs];
#pragma unroll
    for (int n = 0; n < 4; n++)
      bfr[n] = *(const bf16x8*)&Bb[(wc * 64 + n * 16 + la) * 32 + kqs];
    asm volatile("s_waitcnt lgkmcnt(0)" ::: "memory");
    __builtin_amdgcn_s_barrier();
    if (kt + 2 < NT) stage(kt & 1, (kt + 2) * 32);
#pragma unroll
    for (int m = 0; m < 4; m++)
#pragma unroll
      for (int n = 0; n < 4; n++)
        acc[m][n] = __builtin_amdgcn_mfma_f32_16x16x32_bf16(af[m], bfr[n], acc[m][n], 0, 0, 0);
  }

  int row0 = mt * 128 + wr * 64;
  int c_of = n0 + wc * 64;
#pragma unroll
  for (int m = 0; m < 4; m++) {
    int rbase = row0 + m * 16 + ((lane >> 4) << 2);
#pragma unroll
    for (int n = 0; n < 4; n++) {
      int c = c_of + n * 16 + la;
      float b1 = be1[e * DFF + c];
      f32x4 a = acc[m][n];
#pragma unroll
      for (int j = 0; j < 4; j++) {
        int rr = rbase + j;
        if (rr < nrows) {
          float v = a[j] + b1;
          H[(size_t)(beg + rr) * DFF + c] = f2bf(gelu_erf(v));
        }
      }
    }
  }
}

// GEMM2: eo[slot, :] = (H[slot] @ we2[e] + be2)*escale + ebias   (bf16, plain stores)
__global__ __launch_bounds__(256, 3) void k_egemm2(const ushort* __restrict__ H,
                                                   const ushort* __restrict__ w2t,
                                                   const float* __restrict__ be2,
                                                   const float* __restrict__ escale,
                                                   const float* __restrict__ ebias,
                                                   const int* __restrict__ offsets,
                                                   const int* __restrict__ tile_e,
                                                   const int* __restrict__ tile_mt,
                                                   ushort* __restrict__ eo) {
  constexpr int GX = DM / 128;            // 8
  constexpr int NWG = GX * MAXT;          // 1088, %8==0
  int id = blockIdx.y * GX + blockIdx.x;
  int wg = (id & 7) * (NWG / 8) + (id >> 3);
  int ty = wg / GX;
  int n0 = (wg % GX) * 128;
  int e = tile_e[ty];
  if (e < 0) return;
  int mt = tile_mt[ty];
  int beg = offsets[e], nrows = offsets[e + 1] - beg;
  const ushort* B = w2t + (size_t)e * DM * DFF;

  __shared__ ushort As[2][4096];
  __shared__ ushort Bs[2][4096];

  int t = threadIdx.x;
  int wave = t >> 6, lane = t & 63;
  int wr = wave >> 1, wc = wave & 1;

  int r_g0 = mt * 128 + (t >> 2);
  int r_g1 = r_g0 + 64;
  int s0 = beg + (r_g0 < nrows ? r_g0 : 0);
  int s1 = beg + (r_g1 < nrows ? r_g1 : 0);
  int acol = (((t & 3) ^ ((t >> 3) & 3)) * 8);
  const ushort* aptr0 = H + (size_t)s0 * DFF + acol;
  const ushort* aptr1 = H + (size_t)s1 * DFF + acol;
  const ushort* bptr0 = B + (size_t)(n0 + (t >> 2)) * DFF + acol;
  const ushort* bptr1 = B + (size_t)(n0 + (t >> 2) + 64) * DFF + acol;
  char* adst = (char*)As + t * 16;
  char* bdst = (char*)Bs + t * 16;

  auto stage = [&](int b, int k0) {
    gl_lds16(aptr0 + k0, adst + b * 8192);
    gl_lds16(aptr1 + k0, adst + b * 8192 + 4096);
    gl_lds16(bptr0 + k0, bdst + b * 8192);
    gl_lds16(bptr1 + k0, bdst + b * 8192 + 4096);
  };

  f32x4 acc[4][4] = {};
  int la = lane & 15;
  int kqs = (((lane >> 4) ^ ((la >> 1) & 3)) * 8);
  constexpr int NT = DFF / 32;

  stage(0, 0);
  stage(1, 32);
  for (int kt = 0; kt < NT; kt++) {
    if (kt + 1 < NT) asm volatile("s_waitcnt vmcnt(4)" ::: "memory");
    else             asm volatile("s_waitcnt vmcnt(0)" ::: "memory");
    __builtin_amdgcn_s_barrier();
    const ushort* Ab = As[kt & 1];
    const ushort* Bb = Bs[kt & 1];
    bf16x8 af[4], bfr[4];
#pragma unroll
    for (int m = 0; m < 4; m++)
      af[m] = *(const bf16x8*)&Ab[(wr * 64 + m * 16 + la) * 32 + kqs];
#pragma unroll
    for (int n = 0; n < 4; n++)
      bfr[n] = *(const bf16x8*)&Bb[(wc * 64 + n * 16 + la) * 32 + kqs];
    asm volatile("s_waitcnt lgkmcnt(0)" ::: "memory");
    __builtin_amdgcn_s_barrier();
    if (kt + 2 < NT) stage(kt & 1, (kt + 2) * 32);
#pragma unroll
    for (int m = 0; m < 4; m++)
#pragma unroll
      for (int n = 0; n < 4; n++)
        acc[m][n] = __builtin_amdgcn_mfma_f32_16x16x32_bf16(af[m], bfr[n], acc[m][n], 0, 0, 0);
  }

  int row0 = mt * 128 + wr * 64;
  int c_of = n0 + wc * 64;
#pragma unroll
  for (int m = 0; m < 4; m++) {
    int rbase = row0 + m * 16 + ((lane >> 4) << 2);
#pragma unroll
    for (int n = 0; n < 4; n++) {
      int c = c_of + n * 16 + la;
      float b2 = be2[e * DM + c];
      float sc = escale[e * DM + c];
      float bb = ebias[e * DM + c];
      f32x4 a = acc[m][n];
#pragma unroll
      for (int j = 0; j < 4; j++) {
        int rr = rbase + j;
        if (rr < nrows) {
          float v = (a[j] + b2) * sc + bb;
          eo[(size_t)(beg + rr) * DM + c] = f2bf(v);
        }
      }
    }
  }
}

// ---------------- gather + residual + LayerNorm ----------------
__global__ __launch_bounds__(256) void k_ln(const float* __restrict__ x,
                                            const ushort* __restrict__ eo,
                                            const int* __restrict__ tok_slot,
                                            const float* __restrict__ gatesw,
                                            const float* __restrict__ gamma,
                                            const float* __restrict__ beta,
                                            float* __restrict__ y) {
  int t = blockIdx.x;
  int s0 = tok_slot[t * 2], s1 = tok_slot[t * 2 + 1];
  float g0 = gatesw[t * 2], g1 = gatesw[t * 2 + 1];
  const float* xr = &x[(size_t)t * DM];
  const ushort* e0 = &eo[(size_t)s0 * DM];
  const ushort* e1 = &eo[(size_t)s1 * DM];
  int tid = threadIdx.x;
  int c0 = tid * 4;
  float4 xv = *(const float4*)&xr[c0];
  ushort4 a0 = *(const ushort4*)&e0[c0];
  ushort4 a1 = *(const ushort4*)&e1[c0];
  float v[4];
  v[0] = xv.x + g0 * bf2f(a0.x) + g1 * bf2f(a1.x);
  v[1] = xv.y + g0 * bf2f(a0.y) + g1 * bf2f(a1.y);
  v[2] = xv.z + g0 * bf2f(a0.z) + g1 * bf2f(a1.z);
  v[3] = xv.w + g0 * bf2f(a0.w) + g1 * bf2f(a1.w);
  float sum = v[0] + v[1] + v[2] + v[3];
  __shared__ float red[4];
  __shared__ float red2[4];
  for (int off = 32; off > 0; off >>= 1) sum += __shfl_down(sum, off);
  if ((tid & 63) == 0) red[tid >> 6] = sum;
  __syncthreads();
  float mu = (red[0] + red[1] + red[2] + red[3]) * (1.f / DM);
  float vs = 0.f;
#pragma unroll
  for (int i = 0; i < 4; i++) { float d = v[i] - mu; vs += d * d; }
  for (int off = 32; off > 0; off >>= 1) vs += __shfl_down(vs, off);
  if ((tid & 63) == 0) red2[tid >> 6] = vs;
  __syncthreads();
  float var = (red2[0] + red2[1] + red2[2] + red2[3]) * (1.f / DM);
  float rs = rsqrtf(var + 1e-5f);
  float4 gm = *(const float4*)&gamma[c0];
  float4 bt = *(const float4*)&beta[c0];
  float4 o;
  o.x = (v[0] - mu) * rs * gm.x + bt.x;
  o.y = (v[1] - mu) * rs * gm.y + bt.y;
  o.z = (v[2] - mu) * rs * gm.z + bt.z;
  o.w = (v[3] - mu) * rs * gm.w + bt.w;
  *(float4*)&y[(size_t)t * DM + c0] = o;
}

extern "C" void kernel_launch(void* const* d_in, const int* in_sizes, int n_in,
                              void* d_out, int out_size, void* d_ws, size_t ws_size,
                              hipStream_t stream) {
  const float* x    = (const float*)d_in[0];
  const float* gw1  = (const float*)d_in[1];
  const float* gb1  = (const float*)d_in[2];
  const float* gw2  = (const float*)d_in[3];
  const float* gb2  = (const float*)d_in[4];
  const float* we1  = (const float*)d_in[5];
  const float* be1  = (const float*)d_in[6];
  const float* we2  = (const float*)d_in[7];
  const float* be2  = (const float*)d_in[8];
  const float* escale = (const float*)d_in[9];
  const float* ebias  = (const float*)d_in[10];
  const float* gamma  = (const float*)d_in[11];
  const float* beta   = (const float*)d_in[12];
  float* y = (float*)d_out;
  float* loss_out = y + (size_t)T_TOK * DM;

  char* w = (char*)d_ws;
  ushort* xh    = (ushort*)w; w += (size_t)T_TOK * DM * 2;
  ushort* xl    = (ushort*)w; w += (size_t)T_TOK * DM * 2;
  ushort* w1t   = (ushort*)w; w += (size_t)NE * DFF * DM * 2;
  ushort* w2t   = (ushort*)w; w += (size_t)NE * DM * DFF * 2;
  ushort* H     = (ushort*)w; w += (size_t)NSLOT * DFF * 2;
  ushort* eo    = (ushort*)w; w += (size_t)NSLOT * DM * 2;
  ushort* w1ht  = (ushort*)w; w += (size_t)DH * DM * 2;
  ushort* w1lt  = (ushort*)w; w += (size_t)DH * DM * 2;
  float* g1     = (float*)w;  w += (size_t)T_TOK * DH * 4;
  float* logits = (float*)w;  w += (size_t)T_TOK * NE * 4;
  int*   topi   = (int*)w;    w += (size_t)T_TOK * 2 * 4;
  float* gatesw = (float*)w;  w += (size_t)T_TOK * 2 * 4;
  int* slot_tok = (int*)w;    w += (size_t)NSLOT * 4;
  int* tok_slot = (int*)w;    w += (size_t)T_TOK * 2 * 4;
  int* counts   = (int*)w;    w += 64;
  int* fill     = (int*)w;    w += 64;
  int* offsets  = (int*)w;    w += 64;
  float* psum   = (float*)w;  w += 64;
  int* tile_e   = (int*)w;    w += MAXT * 4 + 32;
  int* tile_mt  = (int*)w;    w += MAXT * 4 + 32;

  k_cvt_x<<<2048, 256, 0, stream>>>(x, xh, xl, T_TOK * DM / 4, counts, fill, psum);
  k_trall<<<dim3(2064, 8), 256, 0, stream>>>(we1, we2, gw1, w1t, w2t, w1ht, w1lt);
  k_gate1m<<<dim3(DH / 128, T_TOK / 128), 256, 0, stream>>>(xh, xl, w1ht, w1lt, gb1, g1);
  k_gate2<<<T_TOK / 4, 256, 0, stream>>>(g1, gw2, gb2, logits);
  k_route<<<T_TOK / 256, 256, 0, stream>>>(logits, topi, gatesw, counts, psum);
  k_scan<<<1, 64, 0, stream>>>(counts, offsets, psum, loss_out, tile_e, tile_mt);
  k_fill<<<T_TOK / 256, 256, 0, stream>>>(topi, offsets, fill, slot_tok, tok_slot);
  k_egemm1<<<dim3(DFF / 128, MAXT), 256, 0, stream>>>(xh, w1t, be1, slot_tok, offsets,
                                                      tile_e, tile_mt, H);
  k_egemm2<<<dim3(DM / 128, MAXT), 256, 0, stream>>>(H, w2t, be2, escale, ebias,
                                                     offsets, tile_e, tile_mt, eo);
  k_ln<<<T_TOK, 256, 0, stream>>>(x, eo, tok_slot, gatesw, gamma, beta, y);
}